// Round 1
// baseline (2428.475 us; speedup 1.0000x reference)
//
#include <hip/hip_runtime.h>
#include <math.h>

#define NEG_SLOPE 0.2f

// ---------------- utility kernels ----------------

__global__ void fill_f32(float* __restrict__ p, float v, int n) {
    int i = blockIdx.x * blockDim.x + threadIdx.x;
    if (i < n) p[i] = v;
}

__device__ __forceinline__ void atomicMaxF(float* addr, float val) {
    // sign-bit split trick (handles -0.0 correctly)
    if ((__float_as_uint(val) >> 31) == 0) {
        atomicMax((int*)addr, __float_as_int(val));
    } else {
        atomicMin((unsigned int*)addr, __float_as_uint(val));
    }
}

// ---------------- GEMM: C[N,M] = A[N,K] * B[K,M], fp32 ----------------
// BM=BN=64, BK=16, 256 threads, 4x4 per thread
__global__ __launch_bounds__(256) void gemm_tile(
        const float* __restrict__ A, const float* __restrict__ B,
        float* __restrict__ C, int N, int K, int M) {
    const int BK = 16;
    __shared__ float As[BK][65];
    __shared__ float Bs[BK][65];
    int tid = threadIdx.x;
    int tx = tid & 15;   // n-dir
    int ty = tid >> 4;   // m-dir
    int row0 = blockIdx.x * 64;
    int col0 = blockIdx.y * 64;
    float acc[4][4] = {};
    for (int k0 = 0; k0 < K; k0 += BK) {
        // A tile 64x16: consecutive tids read consecutive k (coalesced 64B rows)
        {
            int kk = tid & 15;
            int mm = tid >> 4;
#pragma unroll
            for (int r = 0; r < 4; ++r) {
                int m = mm + r * 16;
                int grow = row0 + m;
                As[kk][m] = (grow < N) ? A[(size_t)grow * K + k0 + kk] : 0.f;
            }
        }
        // B tile 16x64: consecutive tids read consecutive n (coalesced)
        {
            int nn = tid & 63;
            int kk = tid >> 6;
#pragma unroll
            for (int r = 0; r < 4; ++r) {
                int k = kk + r * 4;
                Bs[k][nn] = B[(size_t)(k0 + k) * M + col0 + nn];
            }
        }
        __syncthreads();
#pragma unroll
        for (int k = 0; k < BK; ++k) {
            float a[4], bb[4];
#pragma unroll
            for (int i = 0; i < 4; ++i) a[i] = As[k][ty * 4 + i];
#pragma unroll
            for (int j = 0; j < 4; ++j) bb[j] = Bs[k][tx * 4 + j];
#pragma unroll
            for (int i = 0; i < 4; ++i)
#pragma unroll
                for (int j = 0; j < 4; ++j)
                    acc[i][j] = fmaf(a[i], bb[j], acc[i][j]);
        }
        __syncthreads();
    }
#pragma unroll
    for (int i = 0; i < 4; ++i) {
        int grow = row0 + ty * 4 + i;
        if (grow < N) {
#pragma unroll
            for (int j = 0; j < 4; ++j)
                C[(size_t)grow * M + col0 + tx * 4 + j] = acc[i][j];
        }
    }
}

// small-M GEMM (layer 3: M=10): one thread per (n, c)
__global__ void gemm_small_n(const float* __restrict__ A, const float* __restrict__ B,
                             float* __restrict__ C, int N, int K, int M) {
    int i = blockIdx.x * blockDim.x + threadIdx.x;
    int tot = N * M;
    int stride = gridDim.x * blockDim.x;
    for (; i < tot; i += stride) {
        int n = i / M, c = i - (i / M) * M;
        const float* a = A + (size_t)n * K;
        float s = 0.f;
        for (int k = 0; k < K; ++k) s = fmaf(a[k], B[(size_t)k * M + c], s);
        C[i] = s;
    }
}

// ---------------- per-node attention dots: al_s/al_d [N,H] ----------------
__global__ void compute_al(const float* __restrict__ h, const float* __restrict__ a_s,
                           const float* __restrict__ a_d, int N, int H, int C,
                           float* __restrict__ al_s, float* __restrict__ al_d) {
    int i = blockIdx.x * blockDim.x + threadIdx.x;
    int tot = N * H;
    int stride = gridDim.x * blockDim.x;
    for (; i < tot; i += stride) {
        int n = i / H, hh = i - (i / H) * H;
        const float* hp = h + (size_t)n * H * C + hh * C;
        const float* as = a_s + hh * C;
        const float* ad = a_d + hh * C;
        float ss = 0.f, sd = 0.f;
        for (int c = 0; c < C; ++c) {
            float v = hp[c];
            ss = fmaf(v, as[c], ss);
            sd = fmaf(v, ad[c], sd);
        }
        al_s[i] = ss;
        al_d[i] = sd;
    }
}

// ---------------- edge pass 1: logits + segment max ----------------
__global__ void edge_max(const float* __restrict__ al_s, const float* __restrict__ al_d,
                         const int* __restrict__ srcI, const int* __restrict__ dstI,
                         int E, int Etot, int H, float* __restrict__ e_buf,
                         float* __restrict__ m) {
    int i = blockIdx.x * blockDim.x + threadIdx.x;
    int tot = Etot * H;
    int stride = gridDim.x * blockDim.x;
    for (; i < tot; i += stride) {
        int e = i / H, hh = i - e * H;
        int s = (e < E) ? srcI[e] : (e - E);
        int d = (e < E) ? dstI[e] : (e - E);
        float v = al_s[s * H + hh] + al_d[d * H + hh];
        v = (v > 0.f) ? v : NEG_SLOPE * v;
        e_buf[i] = v;
        atomicMaxF(&m[d * H + hh], v);
    }
}

// ---------------- edge pass 2: exp + segment sum ----------------
__global__ void edge_expsum(const int* __restrict__ srcI, const int* __restrict__ dstI,
                            int E, int Etot, int H, const float* __restrict__ m,
                            float* __restrict__ e_buf, float* __restrict__ denom) {
    int i = blockIdx.x * blockDim.x + threadIdx.x;
    int tot = Etot * H;
    int stride = gridDim.x * blockDim.x;
    for (; i < tot; i += stride) {
        int e = i / H, hh = i - e * H;
        int d = (e < E) ? dstI[e] : (e - E);
        float ex = expf(e_buf[i] - m[d * H + hh]);
        e_buf[i] = ex;
        atomicAdd(&denom[d * H + hh], ex);
    }
}

// ---------------- edge pass 3: weighted scatter-aggregate ----------------
// one 64-lane wave per edge; lane = channel
__global__ void edge_aggregate(const float* __restrict__ h, const float* __restrict__ ex,
                               const float* __restrict__ denom,
                               const int* __restrict__ srcI, const int* __restrict__ dstI,
                               int E, int Etot, int H, int C, float* __restrict__ out) {
    int lane = threadIdx.x & 63;
    int gw = (blockIdx.x * blockDim.x + threadIdx.x) >> 6;
    int nw = (gridDim.x * blockDim.x) >> 6;
    for (int e = gw; e < Etot; e += nw) {
        int s = (e < E) ? srcI[e] : (e - E);
        int d = (e < E) ? dstI[e] : (e - E);
        for (int hh = 0; hh < H; ++hh) {
            float alpha = ex[e * H + hh] / (denom[d * H + hh] + 1e-16f);
            if (lane < C) {
                atomicAdd(&out[(size_t)d * H * C + hh * C + lane],
                          h[(size_t)s * H * C + hh * C + lane] * alpha);
            }
        }
    }
}

// ---------------- bias + optional ELU ----------------
__global__ void bias_act(float* __restrict__ out, const float* __restrict__ b,
                         int N, int M, int do_elu) {
    int i = blockIdx.x * blockDim.x + threadIdx.x;
    int tot = N * M;
    int stride = gridDim.x * blockDim.x;
    for (; i < tot; i += stride) {
        int j = i - (i / M) * M;
        float v = out[i] + b[j];
        if (do_elu) v = (v > 0.f) ? v : expm1f(v);
        out[i] = v;
    }
}

// ---------------- mean pool ----------------
__global__ void mean_pool(const float* __restrict__ h3, int N, int M,
                          float* __restrict__ pooled) {
    __shared__ float sh[16];
    if (threadIdx.x < M) sh[threadIdx.x] = 0.f;
    __syncthreads();
    int i = blockIdx.x * blockDim.x + threadIdx.x;
    int tot = N * M;
    int stride = gridDim.x * blockDim.x;
    for (; i < tot; i += stride) {
        atomicAdd(&sh[i - (i / M) * M], h3[i]);
    }
    __syncthreads();
    if (threadIdx.x < M) atomicAdd(&pooled[threadIdx.x], sh[threadIdx.x]);
}

__global__ void log_softmax_out(const float* __restrict__ pooled, int N, int M,
                                float* __restrict__ out) {
    if (threadIdx.x == 0) {
        float p[16];
        float mx = -INFINITY;
        for (int c = 0; c < M; ++c) {
            p[c] = pooled[c] / (float)N;
            mx = fmaxf(mx, p[c]);
        }
        float s = 0.f;
        for (int c = 0; c < M; ++c) s += expf(p[c] - mx);
        float ls = logf(s);
        for (int c = 0; c < M; ++c) out[c] = p[c] - mx - ls;
    }
}

// ---------------- host-side layer driver ----------------
static void run_layer(const float* xin, const float* W, const float* a_s,
                      const float* a_d, const float* b, int N, int K, int H, int C,
                      const int* srcI, const int* dstI, int E, int Etot,
                      float* h_lin, float* h_out, float* e_buf, float* al_s,
                      float* al_d, float* mbuf, float* dbuf, bool elu,
                      hipStream_t stream) {
    int M = H * C;
    if (M % 64 == 0) {
        dim3 g((N + 63) / 64, M / 64);
        gemm_tile<<<g, 256, 0, stream>>>(xin, W, h_lin, N, K, M);
    } else {
        int tot = N * M;
        gemm_small_n<<<(tot + 255) / 256, 256, 0, stream>>>(xin, W, h_lin, N, K, M);
    }
    {
        int tot = N * H;
        compute_al<<<(tot + 255) / 256, 256, 0, stream>>>(h_lin, a_s, a_d, N, H, C,
                                                          al_s, al_d);
        fill_f32<<<(tot + 255) / 256, 256, 0, stream>>>(mbuf, -INFINITY, tot);
    }
    hipMemsetAsync(dbuf, 0, (size_t)N * H * sizeof(float), stream);
    hipMemsetAsync(h_out, 0, (size_t)N * M * sizeof(float), stream);
    {
        int tot = Etot * H;
        int blocks = (tot + 255) / 256;
        edge_max<<<blocks, 256, 0, stream>>>(al_s, al_d, srcI, dstI, E, Etot, H,
                                             e_buf, mbuf);
        edge_expsum<<<blocks, 256, 0, stream>>>(srcI, dstI, E, Etot, H, mbuf, e_buf,
                                                dbuf);
    }
    edge_aggregate<<<2048, 256, 0, stream>>>(h_lin, e_buf, dbuf, srcI, dstI, E, Etot,
                                             H, C, h_out);
    bias_act<<<4096, 256, 0, stream>>>(h_out, b, N, M, elu ? 1 : 0);
}

extern "C" void kernel_launch(void* const* d_in, const int* in_sizes, int n_in,
                              void* d_out, int out_size, void* d_ws, size_t ws_size,
                              hipStream_t stream) {
    const float* x   = (const float*)d_in[0];
    const int*   ei  = (const int*)d_in[1];
    const float* W1  = (const float*)d_in[2];
    const float* as1 = (const float*)d_in[3];
    const float* ad1 = (const float*)d_in[4];
    const float* b1  = (const float*)d_in[5];
    const float* W2  = (const float*)d_in[6];
    const float* as2 = (const float*)d_in[7];
    const float* ad2 = (const float*)d_in[8];
    const float* b2  = (const float*)d_in[9];
    const float* W3  = (const float*)d_in[10];
    const float* as3 = (const float*)d_in[11];
    const float* ad3 = (const float*)d_in[12];
    const float* b3  = (const float*)d_in[13];
    float* out = (float*)d_out;

    const int N = in_sizes[0] / 128;   // 50000
    const int E = in_sizes[1] / 2;     // 800000
    const int Etot = E + N;            // with self-loops
    const int* srcI = ei;
    const int* dstI = ei + E;

    float* ws = (float*)d_ws;
    size_t off = 0;
    float* h_lin = ws + off; off += (size_t)N * 256;
    float* out_a = ws + off; off += (size_t)N * 256;
    float* out_b = ws + off; off += (size_t)N * 256;
    float* e_buf = ws + off; off += (size_t)Etot * 4;
    float* al_s  = ws + off; off += (size_t)N * 4;
    float* al_d  = ws + off; off += (size_t)N * 4;
    float* mbuf  = ws + off; off += (size_t)N * 4;
    float* dbuf  = ws + off; off += (size_t)N * 4;
    float* pooled = ws + off; off += 16;

    // layer 1: x[N,128] -> out_a[N,256], ELU
    run_layer(x, W1, as1, ad1, b1, N, 128, 4, 64, srcI, dstI, E, Etot,
              h_lin, out_a, e_buf, al_s, al_d, mbuf, dbuf, true, stream);
    // layer 2: out_a -> out_b, ELU
    run_layer(out_a, W2, as2, ad2, b2, N, 256, 4, 64, srcI, dstI, E, Etot,
              h_lin, out_b, e_buf, al_s, al_d, mbuf, dbuf, true, stream);
    // layer 3: out_b -> out_a[N,10] (reuse), no ELU, heads=1
    run_layer(out_b, W3, as3, ad3, b3, N, 256, 1, 10, srcI, dstI, E, Etot,
              h_lin, out_a, e_buf, al_s, al_d, mbuf, dbuf, false, stream);

    hipMemsetAsync(pooled, 0, 16 * sizeof(float), stream);
    mean_pool<<<1024, 256, 0, stream>>>(out_a, N, 10, pooled);
    log_softmax_out<<<1, 64, 0, stream>>>(pooled, N, 10, out);
}

// Round 2
// 1021.013 us; speedup vs baseline: 2.3785x; 2.3785x over previous
//
#include <hip/hip_runtime.h>
#include <math.h>

#define NEG_SLOPE 0.2f

// ---------------- GEMM: C[N,M] = A[N,K] * B[K,M], fp32 ----------------
__global__ __launch_bounds__(256) void gemm_tile(
        const float* __restrict__ A, const float* __restrict__ B,
        float* __restrict__ C, int N, int K, int M) {
    const int BK = 16;
    __shared__ float As[BK][65];
    __shared__ float Bs[BK][65];
    int tid = threadIdx.x;
    int tx = tid & 15;   // n-dir
    int ty = tid >> 4;   // m-dir
    int row0 = blockIdx.x * 64;
    int col0 = blockIdx.y * 64;
    float acc[4][4] = {};
    for (int k0 = 0; k0 < K; k0 += BK) {
        {
            int kk = tid & 15;
            int mm = tid >> 4;
#pragma unroll
            for (int r = 0; r < 4; ++r) {
                int m = mm + r * 16;
                int grow = row0 + m;
                As[kk][m] = (grow < N) ? A[(size_t)grow * K + k0 + kk] : 0.f;
            }
        }
        {
            int nn = tid & 63;
            int kk = tid >> 6;
#pragma unroll
            for (int r = 0; r < 4; ++r) {
                int k = kk + r * 4;
                Bs[k][nn] = B[(size_t)(k0 + k) * M + col0 + nn];
            }
        }
        __syncthreads();
#pragma unroll
        for (int k = 0; k < BK; ++k) {
            float a[4], bb[4];
#pragma unroll
            for (int i = 0; i < 4; ++i) a[i] = As[k][ty * 4 + i];
#pragma unroll
            for (int j = 0; j < 4; ++j) bb[j] = Bs[k][tx * 4 + j];
#pragma unroll
            for (int i = 0; i < 4; ++i)
#pragma unroll
                for (int j = 0; j < 4; ++j)
                    acc[i][j] = fmaf(a[i], bb[j], acc[i][j]);
        }
        __syncthreads();
    }
#pragma unroll
    for (int i = 0; i < 4; ++i) {
        int grow = row0 + ty * 4 + i;
        if (grow < N) {
#pragma unroll
            for (int j = 0; j < 4; ++j)
                C[(size_t)grow * M + col0 + tx * 4 + j] = acc[i][j];
        }
    }
}

// small-M GEMM (layer 3: M=10)
__global__ void gemm_small_n(const float* __restrict__ A, const float* __restrict__ B,
                             float* __restrict__ C, int N, int K, int M) {
    int i = blockIdx.x * blockDim.x + threadIdx.x;
    int tot = N * M;
    int stride = gridDim.x * blockDim.x;
    for (; i < tot; i += stride) {
        int n = i / M, c = i - (i / M) * M;
        const float* a = A + (size_t)n * K;
        float s = 0.f;
        for (int k = 0; k < K; ++k) s = fmaf(a[k], B[(size_t)k * M + c], s);
        C[i] = s;
    }
}

// ---------------- per-node attention dots ----------------
__global__ void compute_al(const float* __restrict__ h, const float* __restrict__ a_s,
                           const float* __restrict__ a_d, int N, int H, int C,
                           float* __restrict__ al_s, float* __restrict__ al_d) {
    int i = blockIdx.x * blockDim.x + threadIdx.x;
    int tot = N * H;
    int stride = gridDim.x * blockDim.x;
    for (; i < tot; i += stride) {
        int n = i / H, hh = i - (i / H) * H;
        const float* hp = h + (size_t)n * H * C + hh * C;
        const float* as = a_s + hh * C;
        const float* ad = a_d + hh * C;
        float ss = 0.f, sd = 0.f;
        for (int c = 0; c < C; ++c) {
            float v = hp[c];
            ss = fmaf(v, as[c], ss);
            sd = fmaf(v, ad[c], sd);
        }
        al_s[i] = ss;
        al_d[i] = sd;
    }
}

// ---------------- CSR build ----------------
__global__ void deg_hist(const int* __restrict__ dstI, int E, int Etot,
                         int* __restrict__ cnt) {
    int e = blockIdx.x * blockDim.x + threadIdx.x;
    if (e < Etot) {
        int d = (e < E) ? dstI[e] : (e - E);
        atomicAdd(&cnt[d], 1);
    }
}

// single-block exclusive scan (wave-scan + cross-wave), 1024 threads
__global__ __launch_bounds__(1024) void scan_excl(const int* __restrict__ cnt,
                                                  int* __restrict__ rp, int N) {
    __shared__ int wsum[16];
    __shared__ int carry_s;
    int lane = threadIdx.x & 63;
    int wid = threadIdx.x >> 6;
    if (threadIdx.x == 0) carry_s = 0;
    __syncthreads();
    for (int base = 0; base < N; base += 1024) {
        int i = base + (int)threadIdx.x;
        int v = (i < N) ? cnt[i] : 0;
        int x = v;
#pragma unroll
        for (int ofs = 1; ofs < 64; ofs <<= 1) {
            int t = __shfl_up(x, ofs, 64);
            if (lane >= ofs) x += t;
        }
        if (lane == 63) wsum[wid] = x;
        __syncthreads();
        if (wid == 0) {
            int y = (lane < 16) ? wsum[lane] : 0;
#pragma unroll
            for (int ofs = 1; ofs < 16; ofs <<= 1) {
                int t = __shfl_up(y, ofs, 64);
                if (lane >= ofs) y += t;
            }
            if (lane < 16) wsum[lane] = y;
        }
        __syncthreads();
        int wofs = (wid > 0) ? wsum[wid - 1] : 0;
        int incl = x + wofs;
        int carry = carry_s;
        if (i < N) rp[i] = carry + incl - v;
        __syncthreads();
        if (threadIdx.x == 1023) carry_s = carry + wsum[15];
        __syncthreads();
    }
    if (threadIdx.x == 0) rp[N] = carry_s;
}

__global__ void copy_i32(const int* __restrict__ src, int* __restrict__ dst, int n) {
    int i = blockIdx.x * blockDim.x + threadIdx.x;
    if (i < n) dst[i] = src[i];
}

// scatter SOURCE node ids grouped by destination
__global__ void csr_scatter(const int* __restrict__ srcI, const int* __restrict__ dstI,
                            int E, int Etot, int* __restrict__ cursor,
                            int* __restrict__ srcp) {
    int e = blockIdx.x * blockDim.x + threadIdx.x;
    if (e < Etot) {
        int s, d;
        if (e < E) { s = srcI[e]; d = dstI[e]; }
        else       { s = e - E;   d = e - E; }
        int pos = atomicAdd(&cursor[d], 1);
        srcp[pos] = s;
    }
}

// ---------------- fused per-destination softmax + aggregate + bias(+ELU) ----
// one 64-lane wave per destination node; no global atomics
template<int H, int C, bool ELU>
__global__ __launch_bounds__(256) void gat_dst_fused(
        const float* __restrict__ h, const float* __restrict__ al_s,
        const float* __restrict__ al_d, const float* __restrict__ b,
        const int* __restrict__ rp, const int* __restrict__ srcp,
        int N, float* __restrict__ out) {
    const int lane = threadIdx.x & 63;
    int w = (blockIdx.x * blockDim.x + threadIdx.x) >> 6;
    int nw = (gridDim.x * blockDim.x) >> 6;
    const int hlane = (H == 1) ? 0 : (lane & (H - 1));
    for (int d = w; d < N; d += nw) {
        int start = rp[d];
        int deg = rp[d + 1] - start;
        float ald[H];
#pragma unroll
        for (int hh = 0; hh < H; ++hh) ald[hh] = al_d[d * H + hh];
        // pass 1: per-head max over incoming edges
        float mx[H];
#pragma unroll
        for (int hh = 0; hh < H; ++hh) mx[hh] = -INFINITY;
        for (int i = lane; i < deg; i += 64) {
            int s = srcp[start + i];
#pragma unroll
            for (int hh = 0; hh < H; ++hh) {
                float v = al_s[s * H + hh] + ald[hh];
                v = (v > 0.f) ? v : NEG_SLOPE * v;
                mx[hh] = fmaxf(mx[hh], v);
            }
        }
#pragma unroll
        for (int hh = 0; hh < H; ++hh)
#pragma unroll
            for (int m = 1; m < 64; m <<= 1)
                mx[hh] = fmaxf(mx[hh], __shfl_xor(mx[hh], m, 64));
        // pass 2: per-head sum of exp
        float sm[H];
#pragma unroll
        for (int hh = 0; hh < H; ++hh) sm[hh] = 0.f;
        for (int i = lane; i < deg; i += 64) {
            int s = srcp[start + i];
#pragma unroll
            for (int hh = 0; hh < H; ++hh) {
                float v = al_s[s * H + hh] + ald[hh];
                v = (v > 0.f) ? v : NEG_SLOPE * v;
                sm[hh] += expf(v - mx[hh]);
            }
        }
#pragma unroll
        for (int hh = 0; hh < H; ++hh) {
#pragma unroll
            for (int m = 1; m < 64; m <<= 1)
                sm[hh] += __shfl_xor(sm[hh], m, 64);
        }
        float inv_l = 1.f / (sm[hlane] + 1e-16f);
        float mx_l = mx[hlane];
        float ald_l = ald[hlane];
        // pass 3: weighted aggregate; lane covers channel `lane` of each head
        float acc[(H * C + 63) / 64];
#pragma unroll
        for (int q = 0; q < (H * C + 63) / 64; ++q) acc[q] = 0.f;
        for (int i = 0; i < deg; ++i) {
            int s = srcp[start + i];
            float v = al_s[s * H + hlane] + ald_l;
            v = (v > 0.f) ? v : NEG_SLOPE * v;
            float alpha_l = expf(v - mx_l) * inv_l;
            if (H == 1) {
                if (lane < C) acc[0] = fmaf(alpha_l, h[(size_t)s * C + lane], acc[0]);
            } else {
#pragma unroll
                for (int hh = 0; hh < H; ++hh) {
                    float a = __shfl(alpha_l, hh, 64);
                    acc[hh] = fmaf(a, h[(size_t)s * (H * C) + hh * C + lane], acc[hh]);
                }
            }
        }
        // epilogue: bias (+ELU), single write
        if (H == 1) {
            if (lane < C) {
                float v = acc[0] + b[lane];
                if (ELU) v = (v > 0.f) ? v : expm1f(v);
                out[(size_t)d * C + lane] = v;
            }
        } else {
#pragma unroll
            for (int hh = 0; hh < H; ++hh) {
                float v = acc[hh] + b[hh * C + lane];
                if (ELU) v = (v > 0.f) ? v : expm1f(v);
                out[(size_t)d * H * C + hh * C + lane] = v;
            }
        }
    }
}

// ---------------- mean pool + log_softmax ----------------
__global__ void mean_pool(const float* __restrict__ h3, int N, int M,
                          float* __restrict__ pooled) {
    __shared__ float sh[16];
    if (threadIdx.x < 16) sh[threadIdx.x] = 0.f;
    __syncthreads();
    int i = blockIdx.x * blockDim.x + threadIdx.x;
    int tot = N * M;
    int stride = gridDim.x * blockDim.x;
    for (; i < tot; i += stride) {
        atomicAdd(&sh[i - (i / M) * M], h3[i]);
    }
    __syncthreads();
    if (threadIdx.x < (unsigned)M) atomicAdd(&pooled[threadIdx.x], sh[threadIdx.x]);
}

__global__ void log_softmax_out(const float* __restrict__ pooled, int N, int M,
                                float* __restrict__ out) {
    if (threadIdx.x == 0) {
        float p[16];
        float mx = -INFINITY;
        for (int c = 0; c < M; ++c) {
            p[c] = pooled[c] / (float)N;
            mx = fmaxf(mx, p[c]);
        }
        float s = 0.f;
        for (int c = 0; c < M; ++c) s += expf(p[c] - mx);
        float ls = logf(s);
        for (int c = 0; c < M; ++c) out[c] = p[c] - mx - ls;
    }
}

extern "C" void kernel_launch(void* const* d_in, const int* in_sizes, int n_in,
                              void* d_out, int out_size, void* d_ws, size_t ws_size,
                              hipStream_t stream) {
    const float* x   = (const float*)d_in[0];
    const int*   ei  = (const int*)d_in[1];
    const float* W1  = (const float*)d_in[2];
    const float* as1 = (const float*)d_in[3];
    const float* ad1 = (const float*)d_in[4];
    const float* b1  = (const float*)d_in[5];
    const float* W2  = (const float*)d_in[6];
    const float* as2 = (const float*)d_in[7];
    const float* ad2 = (const float*)d_in[8];
    const float* b2  = (const float*)d_in[9];
    const float* W3  = (const float*)d_in[10];
    const float* as3 = (const float*)d_in[11];
    const float* ad3 = (const float*)d_in[12];
    const float* b3  = (const float*)d_in[13];
    float* out = (float*)d_out;

    const int N = in_sizes[0] / 128;   // 50000
    const int E = in_sizes[1] / 2;     // 800000
    const int Etot = E + N;
    const int* srcI = ei;
    const int* dstI = ei + E;

    float* ws = (float*)d_ws;
    size_t off = 0;
    float* h_lin = ws + off; off += (size_t)N * 256;
    float* out_a = ws + off; off += (size_t)N * 256;
    float* out_b = ws + off; off += (size_t)N * 256;
    float* al_s  = ws + off; off += (size_t)N * 4;
    float* al_d  = ws + off; off += (size_t)N * 4;
    int* cnt    = (int*)(ws + off); off += (size_t)N;
    int* rp     = (int*)(ws + off); off += (size_t)N + 1;
    int* cursor = (int*)(ws + off); off += (size_t)N;
    int* srcp   = (int*)(ws + off); off += (size_t)Etot;
    float* pooled = ws + off; off += 16;

    // ---- build CSR once (shared by all 3 layers) ----
    hipMemsetAsync(cnt, 0, (size_t)N * sizeof(int), stream);
    deg_hist<<<(Etot + 255) / 256, 256, 0, stream>>>(dstI, E, Etot, cnt);
    scan_excl<<<1, 1024, 0, stream>>>(cnt, rp, N);
    copy_i32<<<(N + 255) / 256, 256, 0, stream>>>(rp, cursor, N);
    csr_scatter<<<(Etot + 255) / 256, 256, 0, stream>>>(srcI, dstI, E, Etot, cursor, srcp);

    const int FUSED_BLOCKS = (N + 3) / 4;  // 4 waves per 256-thread block

    // ---- layer 1: x[N,128] -> out_a[N,256], ELU ----
    {
        dim3 g((N + 63) / 64, 4);
        gemm_tile<<<g, 256, 0, stream>>>(x, W1, h_lin, N, 128, 256);
        compute_al<<<(N * 4 + 255) / 256, 256, 0, stream>>>(h_lin, as1, ad1, N, 4, 64,
                                                            al_s, al_d);
        gat_dst_fused<4, 64, true><<<FUSED_BLOCKS, 256, 0, stream>>>(
            h_lin, al_s, al_d, b1, rp, srcp, N, out_a);
    }
    // ---- layer 2: out_a -> out_b, ELU ----
    {
        dim3 g((N + 63) / 64, 4);
        gemm_tile<<<g, 256, 0, stream>>>(out_a, W2, h_lin, N, 256, 256);
        compute_al<<<(N * 4 + 255) / 256, 256, 0, stream>>>(h_lin, as2, ad2, N, 4, 64,
                                                            al_s, al_d);
        gat_dst_fused<4, 64, true><<<FUSED_BLOCKS, 256, 0, stream>>>(
            h_lin, al_s, al_d, b2, rp, srcp, N, out_b);
    }
    // ---- layer 3: out_b -> out_a[N,10], heads=1, no ELU ----
    {
        gemm_small_n<<<2048, 256, 0, stream>>>(out_b, W3, h_lin, N, 256, 10);
        compute_al<<<(N + 255) / 256, 256, 0, stream>>>(h_lin, as3, ad3, N, 1, 10,
                                                        al_s, al_d);
        gat_dst_fused<1, 10, false><<<FUSED_BLOCKS, 256, 0, stream>>>(
            h_lin, al_s, al_d, b3, rp, srcp, N, out_a);
    }

    hipMemsetAsync(pooled, 0, 16 * sizeof(float), stream);
    mean_pool<<<1024, 256, 0, stream>>>(out_a, N, 10, pooled);
    log_softmax_out<<<1, 64, 0, stream>>>(pooled, N, 10, out);
}

// Round 3
// 608.353 us; speedup vs baseline: 3.9919x; 1.6783x over previous
//
#include <hip/hip_runtime.h>
#include <math.h>

#define NEG_SLOPE 0.2f

typedef __attribute__((ext_vector_type(8))) short bf16x8;
typedef __attribute__((ext_vector_type(4))) float f32x4;
typedef unsigned short u16;
typedef __attribute__((ext_vector_type(4))) unsigned short u16x4;

__device__ __forceinline__ float b2f(u16 u) {
    return __uint_as_float(((unsigned)u) << 16);
}
__device__ __forceinline__ u16 f2b(float f) {
    unsigned u = __float_as_uint(f);
    unsigned r = (u + 0x7fffu + ((u >> 16) & 1u)) >> 16;
    return (u16)r;
}

// ---------------- casts / transposes ----------------
__global__ void cast_f2b4(const float* __restrict__ in, u16* __restrict__ out, int n4) {
    int i = blockIdx.x * blockDim.x + threadIdx.x;
    if (i < n4) {
        float4 v = *reinterpret_cast<const float4*>(&in[i * 4]);
        u16x4 o;
        o[0] = f2b(v.x); o[1] = f2b(v.y); o[2] = f2b(v.z); o[3] = f2b(v.w);
        *reinterpret_cast<u16x4*>(&out[i * 4]) = o;
    }
}

// W[K][M] fp32 -> Wt[M][K] bf16
__global__ void transpose_w(const float* __restrict__ W, u16* __restrict__ Wt,
                            int K, int M) {
    int i = blockIdx.x * blockDim.x + threadIdx.x;
    if (i < K * M) {
        int m = i / K, k = i - m * K;
        Wt[i] = f2b(W[(size_t)k * M + m]);
    }
}

// ---------------- MFMA GEMM: C[N,M] bf16 = A[N,K] bf16 * Bt[M,K]^T ----------
// BM=BN=128, BK=64, 4 waves (2x2), each wave 64x64 via 4x4 16x16x32 frags.
// LDS XOR-swizzle: within each 128B row, 16B slot s stored at s^(row&7).
__global__ __launch_bounds__(256) void gemm_mfma(
        const u16* __restrict__ A, const u16* __restrict__ Bt,
        u16* __restrict__ C, int N, int K, int M) {
    __shared__ u16 As[128 * 64];
    __shared__ u16 Bs[128 * 64];
    const int tid = threadIdx.x;
    const int lane = tid & 63;
    const int wid = tid >> 6;
    const int wr = wid >> 1, wc = wid & 1;
    const int row0 = blockIdx.x * 128;
    const int col0 = blockIdx.y * 128;
    f32x4 acc[4][4] = {};
    for (int k0 = 0; k0 < K; k0 += 64) {
        if (k0) __syncthreads();
#pragma unroll
        for (int i = 0; i < 4; ++i) {
            int chunk = i * 256 + tid;      // 0..1023, 16B each
            int row = chunk >> 3;
            int slot = chunk & 7;
            int grow = row0 + row; if (grow >= N) grow = N - 1;
            bf16x8 v = *reinterpret_cast<const bf16x8*>(&A[(size_t)grow * K + k0 + slot * 8]);
            int swz = (chunk & ~7) | (slot ^ (row & 7));
            *reinterpret_cast<bf16x8*>(&As[swz * 8]) = v;
        }
#pragma unroll
        for (int i = 0; i < 4; ++i) {
            int chunk = i * 256 + tid;
            int row = chunk >> 3;
            int slot = chunk & 7;
            int gcol = col0 + row;          // M is a multiple of 128
            bf16x8 v = *reinterpret_cast<const bf16x8*>(&Bt[(size_t)gcol * K + k0 + slot * 8]);
            int swz = (chunk & ~7) | (slot ^ (row & 7));
            *reinterpret_cast<bf16x8*>(&Bs[swz * 8]) = v;
        }
        __syncthreads();
#pragma unroll
        for (int kk = 0; kk < 2; ++kk) {
            bf16x8 ax[4], bx[4];
#pragma unroll
            for (int m = 0; m < 4; ++m) {
                int row = wr * 64 + m * 16 + (lane & 15);
                int slot = kk * 4 + (lane >> 4);
                ax[m] = *reinterpret_cast<const bf16x8*>(&As[(row * 8 + (slot ^ (row & 7))) * 8]);
            }
#pragma unroll
            for (int n = 0; n < 4; ++n) {
                int row = wc * 64 + n * 16 + (lane & 15);
                int slot = kk * 4 + (lane >> 4);
                bx[n] = *reinterpret_cast<const bf16x8*>(&Bs[(row * 8 + (slot ^ (row & 7))) * 8]);
            }
#pragma unroll
            for (int m = 0; m < 4; ++m)
#pragma unroll
                for (int n = 0; n < 4; ++n)
                    acc[m][n] = __builtin_amdgcn_mfma_f32_16x16x32_bf16(
                        ax[m], bx[n], acc[m][n], 0, 0, 0);
        }
    }
    const int crow = row0 + wr * 64;
    const int ccol = col0 + wc * 64;
#pragma unroll
    for (int m = 0; m < 4; ++m)
#pragma unroll
        for (int n = 0; n < 4; ++n)
#pragma unroll
            for (int r = 0; r < 4; ++r) {
                int rg = crow + m * 16 + (lane >> 4) * 4 + r;
                int cg = ccol + n * 16 + (lane & 15);
                if (rg < N) C[(size_t)rg * M + cg] = f2b(acc[m][n][r]);
            }
}

// ---------------- per-node attention dots (bf16 h, H=4, C=64) --------------
__global__ void compute_al_b(const u16* __restrict__ h, const float* __restrict__ a_s,
                             const float* __restrict__ a_d, int N,
                             float* __restrict__ al_s, float* __restrict__ al_d) {
    int i = blockIdx.x * blockDim.x + threadIdx.x;   // n*4 + head
    if (i < N * 4) {
        int hh = i & 3;
        const u16* hp = h + (size_t)(i >> 2) * 256 + hh * 64;
        const float* as = a_s + hh * 64;
        const float* ad = a_d + hh * 64;
        float ss = 0.f, sd = 0.f;
        for (int c0 = 0; c0 < 64; c0 += 8) {
            bf16x8 v = *reinterpret_cast<const bf16x8*>(&hp[c0]);
#pragma unroll
            for (int j = 0; j < 8; ++j) {
                float f = b2f((u16)v[j]);
                ss = fmaf(f, as[c0 + j], ss);
                sd = fmaf(f, ad[c0 + j], sd);
            }
        }
        al_s[i] = ss; al_d[i] = sd;
    }
}

// fp32 h, H=1, C=10 (layer 3)
__global__ void compute_al_f(const float* __restrict__ h, const float* __restrict__ a_s,
                             const float* __restrict__ a_d, int N,
                             float* __restrict__ al_s, float* __restrict__ al_d) {
    int n = blockIdx.x * blockDim.x + threadIdx.x;
    if (n < N) {
        const float* hp = h + (size_t)n * 10;
        float ss = 0.f, sd = 0.f;
#pragma unroll
        for (int c = 0; c < 10; ++c) {
            ss = fmaf(hp[c], a_s[c], ss);
            sd = fmaf(hp[c], a_d[c], sd);
        }
        al_s[n] = ss; al_d[n] = sd;
    }
}

// ---------------- CSR build ----------------
__global__ void deg_hist(const int* __restrict__ dstI, int E, int Etot,
                         int* __restrict__ cnt) {
    int e = blockIdx.x * blockDim.x + threadIdx.x;
    if (e < Etot) {
        int d = (e < E) ? dstI[e] : (e - E);
        atomicAdd(&cnt[d], 1);
    }
}

__global__ __launch_bounds__(1024) void scan_excl(const int* __restrict__ cnt,
                                                  int* __restrict__ rp, int N) {
    __shared__ int wsum[16];
    __shared__ int carry_s;
    int lane = threadIdx.x & 63;
    int wid = threadIdx.x >> 6;
    if (threadIdx.x == 0) carry_s = 0;
    __syncthreads();
    for (int base = 0; base < N; base += 1024) {
        int i = base + (int)threadIdx.x;
        int v = (i < N) ? cnt[i] : 0;
        int x = v;
#pragma unroll
        for (int ofs = 1; ofs < 64; ofs <<= 1) {
            int t = __shfl_up(x, ofs, 64);
            if (lane >= ofs) x += t;
        }
        if (lane == 63) wsum[wid] = x;
        __syncthreads();
        if (wid == 0) {
            int y = (lane < 16) ? wsum[lane] : 0;
#pragma unroll
            for (int ofs = 1; ofs < 16; ofs <<= 1) {
                int t = __shfl_up(y, ofs, 64);
                if (lane >= ofs) y += t;
            }
            if (lane < 16) wsum[lane] = y;
        }
        __syncthreads();
        int wofs = (wid > 0) ? wsum[wid - 1] : 0;
        int incl = x + wofs;
        int carry = carry_s;
        if (i < N) rp[i] = carry + incl - v;
        __syncthreads();
        if (threadIdx.x == 1023) carry_s = carry + wsum[15];
        __syncthreads();
    }
    if (threadIdx.x == 0) rp[N] = carry_s;
}

__global__ void copy_i32(const int* __restrict__ src, int* __restrict__ dst, int n) {
    int i = blockIdx.x * blockDim.x + threadIdx.x;
    if (i < n) dst[i] = src[i];
}

__global__ void csr_scatter(const int* __restrict__ srcI, const int* __restrict__ dstI,
                            int E, int Etot, int* __restrict__ cursor,
                            int* __restrict__ srcp) {
    int e = blockIdx.x * blockDim.x + threadIdx.x;
    if (e < Etot) {
        int s, d;
        if (e < E) { s = srcI[e]; d = dstI[e]; }
        else       { s = e - E;   d = e - E; }
        int pos = atomicAdd(&cursor[d], 1);
        srcp[pos] = s;
    }
}

// ---------------- fused per-destination softmax+aggregate+bias(+ELU) -------
__device__ __forceinline__ float ldh(const u16* p)   { return b2f(*p); }
__device__ __forceinline__ float ldh(const float* p) { return *p; }
__device__ __forceinline__ void  sth(u16* p, float v)   { *p = f2b(v); }
__device__ __forceinline__ void  sth(float* p, float v) { *p = v; }

template<int H, int C, bool ELU, typename TI, typename TO>
__global__ __launch_bounds__(256) void gat_dst_fused(
        const TI* __restrict__ h, const float* __restrict__ al_s,
        const float* __restrict__ al_d, const float* __restrict__ b,
        const int* __restrict__ rp, const int* __restrict__ srcp,
        int N, TO* __restrict__ out) {
    const int lane = threadIdx.x & 63;
    int w = (blockIdx.x * blockDim.x + threadIdx.x) >> 6;
    int nw = (gridDim.x * blockDim.x) >> 6;
    const int hlane = (H == 1) ? 0 : (lane & (H - 1));
    for (int d = w; d < N; d += nw) {
        int start = rp[d];
        int deg = rp[d + 1] - start;
        float ald[H];
#pragma unroll
        for (int hh = 0; hh < H; ++hh) ald[hh] = al_d[d * H + hh];
        float mx[H];
#pragma unroll
        for (int hh = 0; hh < H; ++hh) mx[hh] = -INFINITY;
        for (int i = lane; i < deg; i += 64) {
            int s = srcp[start + i];
            float als[H];
            if (H == 4) {
                float4 t = *reinterpret_cast<const float4*>(&al_s[s * 4]);
                als[0] = t.x; als[1] = t.y; als[2] = t.z; als[3] = t.w;
            } else {
                als[0] = al_s[s];
            }
#pragma unroll
            for (int hh = 0; hh < H; ++hh) {
                float v = als[hh] + ald[hh];
                v = (v > 0.f) ? v : NEG_SLOPE * v;
                mx[hh] = fmaxf(mx[hh], v);
            }
        }
#pragma unroll
        for (int hh = 0; hh < H; ++hh)
#pragma unroll
            for (int m = 1; m < 64; m <<= 1)
                mx[hh] = fmaxf(mx[hh], __shfl_xor(mx[hh], m, 64));
        float sm[H];
#pragma unroll
        for (int hh = 0; hh < H; ++hh) sm[hh] = 0.f;
        for (int i = lane; i < deg; i += 64) {
            int s = srcp[start + i];
            float als[H];
            if (H == 4) {
                float4 t = *reinterpret_cast<const float4*>(&al_s[s * 4]);
                als[0] = t.x; als[1] = t.y; als[2] = t.z; als[3] = t.w;
            } else {
                als[0] = al_s[s];
            }
#pragma unroll
            for (int hh = 0; hh < H; ++hh) {
                float v = als[hh] + ald[hh];
                v = (v > 0.f) ? v : NEG_SLOPE * v;
                sm[hh] += expf(v - mx[hh]);
            }
        }
#pragma unroll
        for (int hh = 0; hh < H; ++hh)
#pragma unroll
            for (int m = 1; m < 64; m <<= 1)
                sm[hh] += __shfl_xor(sm[hh], m, 64);
        float inv_l = 1.f / (sm[hlane] + 1e-16f);
        float mx_l = mx[hlane];
        float ald_l = ald[hlane];
        float acc[(H * C + 63) / 64];
#pragma unroll
        for (int q = 0; q < (H * C + 63) / 64; ++q) acc[q] = 0.f;
        for (int i = 0; i < deg; ++i) {
            int s = srcp[start + i];
            float v = al_s[s * H + hlane] + ald_l;
            v = (v > 0.f) ? v : NEG_SLOPE * v;
            float alpha_l = expf(v - mx_l) * inv_l;
            if (H == 1) {
                if (lane < C) acc[0] = fmaf(alpha_l, ldh(&h[(size_t)s * C + lane]), acc[0]);
            } else {
#pragma unroll
                for (int hh = 0; hh < H; ++hh) {
                    float a = __shfl(alpha_l, hh, 64);
                    acc[hh] = fmaf(a, ldh(&h[(size_t)s * (H * C) + hh * C + lane]), acc[hh]);
                }
            }
        }
        if (H == 1) {
            if (lane < C) {
                float v = acc[0] + b[lane];
                if (ELU) v = (v > 0.f) ? v : expm1f(v);
                sth(&out[(size_t)d * C + lane], v);
            }
        } else {
#pragma unroll
            for (int hh = 0; hh < H; ++hh) {
                float v = acc[hh] + b[hh * C + lane];
                if (ELU) v = (v > 0.f) ? v : expm1f(v);
                sth(&out[(size_t)d * H * C + hh * C + lane], v);
            }
        }
    }
}

// ---------------- layer-3 GEMM: [N,256]bf16 x [256,10]f32 -> [N,10]f32 ------
// one wave per node; W3 slice held in registers (40/lane)
__global__ __launch_bounds__(256) void gemm3_wave(const u16* __restrict__ A,
                                                  const float* __restrict__ W,
                                                  float* __restrict__ C, int N) {
    const int lane = threadIdx.x & 63;
    int w = (blockIdx.x * blockDim.x + threadIdx.x) >> 6;
    int nw = (gridDim.x * blockDim.x) >> 6;
    float wreg[4][10];
#pragma unroll
    for (int j = 0; j < 4; ++j)
#pragma unroll
        for (int c = 0; c < 10; ++c)
            wreg[j][c] = W[(lane * 4 + j) * 10 + c];
    for (int d = w; d < N; d += nw) {
        u16x4 av = *reinterpret_cast<const u16x4*>(&A[(size_t)d * 256 + lane * 4]);
        float p[10];
#pragma unroll
        for (int c = 0; c < 10; ++c) p[c] = 0.f;
#pragma unroll
        for (int j = 0; j < 4; ++j) {
            float a = b2f(av[j]);
#pragma unroll
            for (int c = 0; c < 10; ++c) p[c] = fmaf(a, wreg[j][c], p[c]);
        }
#pragma unroll
        for (int c = 0; c < 10; ++c)
#pragma unroll
            for (int m = 1; m < 64; m <<= 1)
                p[c] += __shfl_xor(p[c], m, 64);
        float outv = p[0];
#pragma unroll
        for (int c = 1; c < 10; ++c) if (lane == c) outv = p[c];
        if (lane < 10) C[(size_t)d * 10 + lane] = outv;
    }
}

// ---------------- mean pool + log_softmax ----------------
__global__ void mean_pool(const float* __restrict__ h3, int N, int M,
                          float* __restrict__ pooled) {
    __shared__ float sh[16];
    if (threadIdx.x < 16) sh[threadIdx.x] = 0.f;
    __syncthreads();
    int i = blockIdx.x * blockDim.x + threadIdx.x;
    int tot = N * M;
    int stride = gridDim.x * blockDim.x;
    for (; i < tot; i += stride) {
        atomicAdd(&sh[i - (i / M) * M], h3[i]);
    }
    __syncthreads();
    if (threadIdx.x < (unsigned)M) atomicAdd(&pooled[threadIdx.x], sh[threadIdx.x]);
}

__global__ void log_softmax_out(const float* __restrict__ pooled, int N, int M,
                                float* __restrict__ out) {
    if (threadIdx.x == 0) {
        float p[16];
        float mx = -INFINITY;
        for (int c = 0; c < M; ++c) {
            p[c] = pooled[c] / (float)N;
            mx = fmaxf(mx, p[c]);
        }
        float s = 0.f;
        for (int c = 0; c < M; ++c) s += expf(p[c] - mx);
        float ls = logf(s);
        for (int c = 0; c < M; ++c) out[c] = p[c] - mx - ls;
    }
}

extern "C" void kernel_launch(void* const* d_in, const int* in_sizes, int n_in,
                              void* d_out, int out_size, void* d_ws, size_t ws_size,
                              hipStream_t stream) {
    const float* x   = (const float*)d_in[0];
    const int*   ei  = (const int*)d_in[1];
    const float* W1  = (const float*)d_in[2];
    const float* as1 = (const float*)d_in[3];
    const float* ad1 = (const float*)d_in[4];
    const float* b1  = (const float*)d_in[5];
    const float* W2  = (const float*)d_in[6];
    const float* as2 = (const float*)d_in[7];
    const float* ad2 = (const float*)d_in[8];
    const float* b2  = (const float*)d_in[9];
    const float* W3  = (const float*)d_in[10];
    const float* as3 = (const float*)d_in[11];
    const float* ad3 = (const float*)d_in[12];
    const float* b3  = (const float*)d_in[13];
    float* out = (float*)d_out;

    const int N = in_sizes[0] / 128;   // 50000
    const int E = in_sizes[1] / 2;     // 800000
    const int Etot = E + N;
    const int* srcI = ei;
    const int* dstI = ei + E;

    char* base = (char*)d_ws;
    size_t off = 0;
    auto alloc = [&](size_t bytes) {
        void* p = base + off;
        off = (off + bytes + 255) & ~(size_t)255;
        return p;
    };
    u16* x_bf  = (u16*)alloc((size_t)N * 128 * 2);
    u16* h_bf  = (u16*)alloc((size_t)N * 256 * 2);
    u16* oa_bf = (u16*)alloc((size_t)N * 256 * 2);
    u16* ob_bf = (u16*)alloc((size_t)N * 256 * 2);
    u16* w1t   = (u16*)alloc(256 * 128 * 2);
    u16* w2t   = (u16*)alloc(256 * 256 * 2);
    float* h3   = (float*)alloc((size_t)N * 10 * 4);
    float* o3   = (float*)alloc((size_t)N * 10 * 4);
    float* al_s = (float*)alloc((size_t)N * 4 * 4);
    float* al_d = (float*)alloc((size_t)N * 4 * 4);
    int* cnt    = (int*)alloc((size_t)N * 4);
    int* rp     = (int*)alloc((size_t)(N + 1) * 4);
    int* cursor = (int*)alloc((size_t)N * 4);
    int* srcp   = (int*)alloc((size_t)Etot * 4);
    float* pooled = (float*)alloc(64);

    // ---- preprocessing: casts, transposes, CSR ----
    cast_f2b4<<<(N * 128 / 4 + 255) / 256, 256, 0, stream>>>(x, x_bf, N * 128 / 4);
    transpose_w<<<(128 * 256 + 255) / 256, 256, 0, stream>>>(W1, w1t, 128, 256);
    transpose_w<<<(256 * 256 + 255) / 256, 256, 0, stream>>>(W2, w2t, 256, 256);
    hipMemsetAsync(cnt, 0, (size_t)N * sizeof(int), stream);
    deg_hist<<<(Etot + 255) / 256, 256, 0, stream>>>(dstI, E, Etot, cnt);
    scan_excl<<<1, 1024, 0, stream>>>(cnt, rp, N);
    copy_i32<<<(N + 255) / 256, 256, 0, stream>>>(rp, cursor, N);
    csr_scatter<<<(Etot + 255) / 256, 256, 0, stream>>>(srcI, dstI, E, Etot, cursor, srcp);

    const int FUSED_BLOCKS = (N + 3) / 4;
    const int GX = (N + 127) / 128;

    // ---- layer 1: x_bf[N,128] -> oa_bf[N,256], ELU ----
    {
        dim3 g(GX, 2);
        gemm_mfma<<<g, 256, 0, stream>>>(x_bf, w1t, h_bf, N, 128, 256);
        compute_al_b<<<(N * 4 + 255) / 256, 256, 0, stream>>>(h_bf, as1, ad1, N, al_s, al_d);
        gat_dst_fused<4, 64, true, u16, u16><<<FUSED_BLOCKS, 256, 0, stream>>>(
            h_bf, al_s, al_d, b1, rp, srcp, N, oa_bf);
    }
    // ---- layer 2: oa_bf -> ob_bf, ELU ----
    {
        dim3 g(GX, 2);
        gemm_mfma<<<g, 256, 0, stream>>>(oa_bf, w2t, h_bf, N, 256, 256);
        compute_al_b<<<(N * 4 + 255) / 256, 256, 0, stream>>>(h_bf, as2, ad2, N, al_s, al_d);
        gat_dst_fused<4, 64, true, u16, u16><<<FUSED_BLOCKS, 256, 0, stream>>>(
            h_bf, al_s, al_d, b2, rp, srcp, N, ob_bf);
    }
    // ---- layer 3: ob_bf[N,256] -> o3[N,10], heads=1, no ELU ----
    {
        gemm3_wave<<<1024, 256, 0, stream>>>(ob_bf, W3, h3, N);
        compute_al_f<<<(N + 255) / 256, 256, 0, stream>>>(h3, as3, ad3, N, al_s, al_d);
        gat_dst_fused<1, 10, false, float, float><<<FUSED_BLOCKS, 256, 0, stream>>>(
            h3, al_s, al_d, b3, rp, srcp, N, o3);
    }

    hipMemsetAsync(pooled, 0, 16 * sizeof(float), stream);
    mean_pool<<<1024, 256, 0, stream>>>(o3, N, 10, pooled);
    log_softmax_out<<<1, 64, 0, stream>>>(pooled, N, 10, out);
}

// Round 4
// 499.795 us; speedup vs baseline: 4.8589x; 1.2172x over previous
//
#include <hip/hip_runtime.h>
#include <math.h>

#define NEG_SLOPE 0.2f

typedef __attribute__((ext_vector_type(8))) short bf16x8;
typedef __attribute__((ext_vector_type(4))) float f32x4;
typedef unsigned short u16;
typedef __attribute__((ext_vector_type(4))) unsigned short u16x4;

__device__ __forceinline__ float b2f(u16 u) {
    return __uint_as_float(((unsigned)u) << 16);
}
__device__ __forceinline__ u16 f2b(float f) {
    unsigned u = __float_as_uint(f);
    unsigned r = (u + 0x7fffu + ((u >> 16) & 1u)) >> 16;
    return (u16)r;
}

// ---------------- casts / transposes ----------------
__global__ void cast_f2b4(const float* __restrict__ in, u16* __restrict__ out, int n4) {
    int i = blockIdx.x * blockDim.x + threadIdx.x;
    if (i < n4) {
        float4 v = *reinterpret_cast<const float4*>(&in[i * 4]);
        u16x4 o;
        o[0] = f2b(v.x); o[1] = f2b(v.y); o[2] = f2b(v.z); o[3] = f2b(v.w);
        *reinterpret_cast<u16x4*>(&out[i * 4]) = o;
    }
}

// W[K][M] fp32 -> Wt[M][K] bf16
__global__ void transpose_w(const float* __restrict__ W, u16* __restrict__ Wt,
                            int K, int M) {
    int i = blockIdx.x * blockDim.x + threadIdx.x;
    if (i < K * M) {
        int m = i / K, k = i - m * K;
        Wt[i] = f2b(W[(size_t)k * M + m]);
    }
}

// ---------------- MFMA GEMM: C[N,M] bf16 = A[N,K] bf16 * Bt[M,K]^T ----------
__global__ __launch_bounds__(256) void gemm_mfma(
        const u16* __restrict__ A, const u16* __restrict__ Bt,
        u16* __restrict__ C, int N, int K, int M) {
    __shared__ u16 As[128 * 64];
    __shared__ u16 Bs[128 * 64];
    const int tid = threadIdx.x;
    const int lane = tid & 63;
    const int wid = tid >> 6;
    const int wr = wid >> 1, wc = wid & 1;
    const int row0 = blockIdx.x * 128;
    const int col0 = blockIdx.y * 128;
    f32x4 acc[4][4] = {};
    for (int k0 = 0; k0 < K; k0 += 64) {
        if (k0) __syncthreads();
#pragma unroll
        for (int i = 0; i < 4; ++i) {
            int chunk = i * 256 + tid;
            int row = chunk >> 3;
            int slot = chunk & 7;
            int grow = row0 + row; if (grow >= N) grow = N - 1;
            bf16x8 v = *reinterpret_cast<const bf16x8*>(&A[(size_t)grow * K + k0 + slot * 8]);
            int swz = (chunk & ~7) | (slot ^ (row & 7));
            *reinterpret_cast<bf16x8*>(&As[swz * 8]) = v;
        }
#pragma unroll
        for (int i = 0; i < 4; ++i) {
            int chunk = i * 256 + tid;
            int row = chunk >> 3;
            int slot = chunk & 7;
            int gcol = col0 + row;
            bf16x8 v = *reinterpret_cast<const bf16x8*>(&Bt[(size_t)gcol * K + k0 + slot * 8]);
            int swz = (chunk & ~7) | (slot ^ (row & 7));
            *reinterpret_cast<bf16x8*>(&Bs[swz * 8]) = v;
        }
        __syncthreads();
#pragma unroll
        for (int kk = 0; kk < 2; ++kk) {
            bf16x8 ax[4], bx[4];
#pragma unroll
            for (int m = 0; m < 4; ++m) {
                int row = wr * 64 + m * 16 + (lane & 15);
                int slot = kk * 4 + (lane >> 4);
                ax[m] = *reinterpret_cast<const bf16x8*>(&As[(row * 8 + (slot ^ (row & 7))) * 8]);
            }
#pragma unroll
            for (int n = 0; n < 4; ++n) {
                int row = wc * 64 + n * 16 + (lane & 15);
                int slot = kk * 4 + (lane >> 4);
                bx[n] = *reinterpret_cast<const bf16x8*>(&Bs[(row * 8 + (slot ^ (row & 7))) * 8]);
            }
#pragma unroll
            for (int m = 0; m < 4; ++m)
#pragma unroll
                for (int n = 0; n < 4; ++n)
                    acc[m][n] = __builtin_amdgcn_mfma_f32_16x16x32_bf16(
                        ax[m], bx[n], acc[m][n], 0, 0, 0);
        }
    }
    const int crow = row0 + wr * 64;
    const int ccol = col0 + wc * 64;
#pragma unroll
    for (int m = 0; m < 4; ++m)
#pragma unroll
        for (int n = 0; n < 4; ++n)
#pragma unroll
            for (int r = 0; r < 4; ++r) {
                int rg = crow + m * 16 + (lane >> 4) * 4 + r;
                int cg = ccol + n * 16 + (lane & 15);
                if (rg < N) C[(size_t)rg * M + cg] = f2b(acc[m][n][r]);
            }
}

// ---------------- per-node attention dots (bf16 h, H=4, C=64) --------------
__global__ void compute_al_b(const u16* __restrict__ h, const float* __restrict__ a_s,
                             const float* __restrict__ a_d, int N,
                             float* __restrict__ al_s, float* __restrict__ al_d) {
    int i = blockIdx.x * blockDim.x + threadIdx.x;   // n*4 + head
    if (i < N * 4) {
        int hh = i & 3;
        const u16* hp = h + (size_t)(i >> 2) * 256 + hh * 64;
        const float* as = a_s + hh * 64;
        const float* ad = a_d + hh * 64;
        float ss = 0.f, sd = 0.f;
        for (int c0 = 0; c0 < 64; c0 += 8) {
            bf16x8 v = *reinterpret_cast<const bf16x8*>(&hp[c0]);
#pragma unroll
            for (int j = 0; j < 8; ++j) {
                float f = b2f((u16)v[j]);
                ss = fmaf(f, as[c0 + j], ss);
                sd = fmaf(f, ad[c0 + j], sd);
            }
        }
        al_s[i] = ss; al_d[i] = sd;
    }
}

// fp32 h, H=1, C=10 (layer 3)
__global__ void compute_al_f(const float* __restrict__ h, const float* __restrict__ a_s,
                             const float* __restrict__ a_d, int N,
                             float* __restrict__ al_s, float* __restrict__ al_d) {
    int n = blockIdx.x * blockDim.x + threadIdx.x;
    if (n < N) {
        const float* hp = h + (size_t)n * 10;
        float ss = 0.f, sd = 0.f;
#pragma unroll
        for (int c = 0; c < 10; ++c) {
            ss = fmaf(hp[c], a_s[c], ss);
            sd = fmaf(hp[c], a_d[c], sd);
        }
        al_s[n] = ss; al_d[n] = sd;
    }
}

// ---------------- CSR build ----------------
__global__ void deg_hist(const int* __restrict__ dstI, int E, int Etot,
                         int* __restrict__ cnt) {
    int e = blockIdx.x * blockDim.x + threadIdx.x;
    if (e < Etot) {
        int d = (e < E) ? dstI[e] : (e - E);
        atomicAdd(&cnt[d], 1);
    }
}

// single-block exclusive scan, 4 elements/thread (writes rp AND cursor)
__global__ __launch_bounds__(1024) void scan_excl4(const int* __restrict__ cnt,
                                                   int* __restrict__ rp,
                                                   int* __restrict__ cursor, int N) {
    __shared__ int wsum[16];
    __shared__ int carry_s;
    int lane = threadIdx.x & 63;
    int wid = threadIdx.x >> 6;
    if (threadIdx.x == 0) carry_s = 0;
    __syncthreads();
    for (int base = 0; base < N; base += 4096) {
        int idx = base + (int)threadIdx.x * 4;
        int a0 = 0, a1 = 0, a2 = 0, a3 = 0;
        if (idx + 3 < N) {
            int4 v = *reinterpret_cast<const int4*>(&cnt[idx]);
            a0 = v.x; a1 = v.y; a2 = v.z; a3 = v.w;
        } else {
            if (idx < N)     a0 = cnt[idx];
            if (idx + 1 < N) a1 = cnt[idx + 1];
            if (idx + 2 < N) a2 = cnt[idx + 2];
        }
        int p1 = a0 + a1, p2 = p1 + a2, p3 = p2 + a3;
        int x = p3;
#pragma unroll
        for (int ofs = 1; ofs < 64; ofs <<= 1) {
            int t = __shfl_up(x, ofs, 64);
            if (lane >= ofs) x += t;
        }
        if (lane == 63) wsum[wid] = x;
        __syncthreads();
        if (wid == 0) {
            int y = (lane < 16) ? wsum[lane] : 0;
#pragma unroll
            for (int ofs = 1; ofs < 16; ofs <<= 1) {
                int t = __shfl_up(y, ofs, 64);
                if (lane >= ofs) y += t;
            }
            if (lane < 16) wsum[lane] = y;
        }
        __syncthreads();
        int wofs = (wid > 0) ? wsum[wid - 1] : 0;
        int carry = carry_s;
        int excl = carry + wofs + (x - p3);
        if (idx < N)     { rp[idx] = excl;          cursor[idx] = excl; }
        if (idx + 1 < N) { rp[idx + 1] = excl + a0; cursor[idx + 1] = excl + a0; }
        if (idx + 2 < N) { rp[idx + 2] = excl + p1; cursor[idx + 2] = excl + p1; }
        if (idx + 3 < N) { rp[idx + 3] = excl + p2; cursor[idx + 3] = excl + p2; }
        __syncthreads();
        if (threadIdx.x == 1023) carry_s = carry + wsum[15];
        __syncthreads();
    }
    if (threadIdx.x == 0) rp[N] = carry_s;
}

__global__ void csr_scatter(const int* __restrict__ srcI, const int* __restrict__ dstI,
                            int E, int Etot, int* __restrict__ cursor,
                            int* __restrict__ srcp) {
    int e = blockIdx.x * blockDim.x + threadIdx.x;
    if (e < Etot) {
        int s, d;
        if (e < E) { s = srcI[e]; d = dstI[e]; }
        else       { s = e - E;   d = e - E; }
        int pos = atomicAdd(&cursor[d], 1);
        srcp[pos] = s;
    }
}

// ---------------- single-pass fused aggregate, H=4, C=64 --------------------
// one wave per destination; lane l owns channels [4l,4l+4), head = l>>4.
// out = (sum_e exp(leaky(logit)) * h_src) / sum_e exp + b  [+ELU]
template<bool ELU>
__global__ __launch_bounds__(256) void gat_fused_h4(
        const u16* __restrict__ h, const float* __restrict__ al_s,
        const float* __restrict__ al_d, const float* __restrict__ b,
        const int* __restrict__ rp, const int* __restrict__ srcp,
        int N, u16* __restrict__ out) {
    const int lane = threadIdx.x & 63;
    const int head = lane >> 4;
    int w = (blockIdx.x * blockDim.x + threadIdx.x) >> 6;
    int nw = (gridDim.x * blockDim.x) >> 6;
    for (int d = w; d < N; d += nw) {
        int i = rp[d], end = rp[d + 1];
        float ald = al_d[d * 4 + head];
        float acc0 = 0.f, acc1 = 0.f, acc2 = 0.f, acc3 = 0.f, L = 0.f;
        for (; i + 2 <= end; i += 2) {
            int s0 = srcp[i], s1 = srcp[i + 1];
            u16x4 h0 = *reinterpret_cast<const u16x4*>(&h[(size_t)s0 * 256 + lane * 4]);
            u16x4 h1 = *reinterpret_cast<const u16x4*>(&h[(size_t)s1 * 256 + lane * 4]);
            float v0 = al_s[s0 * 4 + head] + ald;
            float v1 = al_s[s1 * 4 + head] + ald;
            v0 = (v0 > 0.f) ? v0 : NEG_SLOPE * v0;
            v1 = (v1 > 0.f) ? v1 : NEG_SLOPE * v1;
            float e0 = expf(v0), e1 = expf(v1);
            L += e0 + e1;
            acc0 = fmaf(e0, b2f((u16)h0[0]), acc0);
            acc1 = fmaf(e0, b2f((u16)h0[1]), acc1);
            acc2 = fmaf(e0, b2f((u16)h0[2]), acc2);
            acc3 = fmaf(e0, b2f((u16)h0[3]), acc3);
            acc0 = fmaf(e1, b2f((u16)h1[0]), acc0);
            acc1 = fmaf(e1, b2f((u16)h1[1]), acc1);
            acc2 = fmaf(e1, b2f((u16)h1[2]), acc2);
            acc3 = fmaf(e1, b2f((u16)h1[3]), acc3);
        }
        if (i < end) {
            int s0 = srcp[i];
            u16x4 h0 = *reinterpret_cast<const u16x4*>(&h[(size_t)s0 * 256 + lane * 4]);
            float v0 = al_s[s0 * 4 + head] + ald;
            v0 = (v0 > 0.f) ? v0 : NEG_SLOPE * v0;
            float e0 = expf(v0);
            L += e0;
            acc0 = fmaf(e0, b2f((u16)h0[0]), acc0);
            acc1 = fmaf(e0, b2f((u16)h0[1]), acc1);
            acc2 = fmaf(e0, b2f((u16)h0[2]), acc2);
            acc3 = fmaf(e0, b2f((u16)h0[3]), acc3);
        }
        float inv = 1.f / (L + 1e-16f);
        float4 bb = *reinterpret_cast<const float4*>(&b[lane * 4]);
        float o0 = fmaf(acc0, inv, bb.x);
        float o1 = fmaf(acc1, inv, bb.y);
        float o2 = fmaf(acc2, inv, bb.z);
        float o3 = fmaf(acc3, inv, bb.w);
        if (ELU) {
            o0 = (o0 > 0.f) ? o0 : expm1f(o0);
            o1 = (o1 > 0.f) ? o1 : expm1f(o1);
            o2 = (o2 > 0.f) ? o2 : expm1f(o2);
            o3 = (o3 > 0.f) ? o3 : expm1f(o3);
        }
        u16x4 ov;
        ov[0] = f2b(o0); ov[1] = f2b(o1); ov[2] = f2b(o2); ov[3] = f2b(o3);
        *reinterpret_cast<u16x4*>(&out[(size_t)d * 256 + lane * 4]) = ov;
    }
}

// single-pass fused aggregate, H=1, C=10, fp32 (layer 3, no ELU)
__global__ __launch_bounds__(256) void gat_fused_h1(
        const float* __restrict__ h, const float* __restrict__ al_s,
        const float* __restrict__ al_d, const float* __restrict__ b,
        const int* __restrict__ rp, const int* __restrict__ srcp,
        int N, float* __restrict__ out) {
    const int lane = threadIdx.x & 63;
    int w = (blockIdx.x * blockDim.x + threadIdx.x) >> 6;
    int nw = (gridDim.x * blockDim.x) >> 6;
    for (int d = w; d < N; d += nw) {
        int i = rp[d], end = rp[d + 1];
        float ald = al_d[d];
        float acc = 0.f, L = 0.f;
        for (; i < end; ++i) {
            int s = srcp[i];
            float v = al_s[s] + ald;
            v = (v > 0.f) ? v : NEG_SLOPE * v;
            float e = expf(v);
            L += e;
            if (lane < 10) acc = fmaf(e, h[(size_t)s * 10 + lane], acc);
        }
        if (lane < 10) out[(size_t)d * 10 + lane] = acc / (L + 1e-16f) + b[lane];
    }
}

// ---------------- layer-3 GEMM: [N,256]bf16 x [256,10]f32 -> [N,10]f32 ------
__global__ __launch_bounds__(256) void gemm3_wave(const u16* __restrict__ A,
                                                  const float* __restrict__ W,
                                                  float* __restrict__ C, int N) {
    const int lane = threadIdx.x & 63;
    int w = (blockIdx.x * blockDim.x + threadIdx.x) >> 6;
    int nw = (gridDim.x * blockDim.x) >> 6;
    float wreg[4][10];
#pragma unroll
    for (int j = 0; j < 4; ++j)
#pragma unroll
        for (int c = 0; c < 10; ++c)
            wreg[j][c] = W[(lane * 4 + j) * 10 + c];
    for (int d = w; d < N; d += nw) {
        u16x4 av = *reinterpret_cast<const u16x4*>(&A[(size_t)d * 256 + lane * 4]);
        float p[10];
#pragma unroll
        for (int c = 0; c < 10; ++c) p[c] = 0.f;
#pragma unroll
        for (int j = 0; j < 4; ++j) {
            float a = b2f(av[j]);
#pragma unroll
            for (int c = 0; c < 10; ++c) p[c] = fmaf(a, wreg[j][c], p[c]);
        }
#pragma unroll
        for (int c = 0; c < 10; ++c)
#pragma unroll
            for (int m = 1; m < 64; m <<= 1)
                p[c] += __shfl_xor(p[c], m, 64);
        float outv = p[0];
#pragma unroll
        for (int c = 1; c < 10; ++c) if (lane == c) outv = p[c];
        if (lane < 10) C[(size_t)d * 10 + lane] = outv;
    }
}

// ---------------- mean pool + log_softmax ----------------
__global__ void mean_pool(const float* __restrict__ h3, int N, int M,
                          float* __restrict__ pooled) {
    __shared__ float sh[16];
    if (threadIdx.x < 16) sh[threadIdx.x] = 0.f;
    __syncthreads();
    int i = blockIdx.x * blockDim.x + threadIdx.x;
    int tot = N * M;
    int stride = gridDim.x * blockDim.x;
    for (; i < tot; i += stride) {
        atomicAdd(&sh[i - (i / M) * M], h3[i]);
    }
    __syncthreads();
    if (threadIdx.x < (unsigned)M) atomicAdd(&pooled[threadIdx.x], sh[threadIdx.x]);
}

__global__ void log_softmax_out(const float* __restrict__ pooled, int N, int M,
                                float* __restrict__ out) {
    if (threadIdx.x == 0) {
        float p[16];
        float mx = -INFINITY;
        for (int c = 0; c < M; ++c) {
            p[c] = pooled[c] / (float)N;
            mx = fmaxf(mx, p[c]);
        }
        float s = 0.f;
        for (int c = 0; c < M; ++c) s += expf(p[c] - mx);
        float ls = logf(s);
        for (int c = 0; c < M; ++c) out[c] = p[c] - mx - ls;
    }
}

extern "C" void kernel_launch(void* const* d_in, const int* in_sizes, int n_in,
                              void* d_out, int out_size, void* d_ws, size_t ws_size,
                              hipStream_t stream) {
    const float* x   = (const float*)d_in[0];
    const int*   ei  = (const int*)d_in[1];
    const float* W1  = (const float*)d_in[2];
    const float* as1 = (const float*)d_in[3];
    const float* ad1 = (const float*)d_in[4];
    const float* b1  = (const float*)d_in[5];
    const float* W2  = (const float*)d_in[6];
    const float* as2 = (const float*)d_in[7];
    const float* ad2 = (const float*)d_in[8];
    const float* b2  = (const float*)d_in[9];
    const float* W3  = (const float*)d_in[10];
    const float* as3 = (const float*)d_in[11];
    const float* ad3 = (const float*)d_in[12];
    const float* b3  = (const float*)d_in[13];
    float* out = (float*)d_out;

    const int N = in_sizes[0] / 128;   // 50000
    const int E = in_sizes[1] / 2;     // 800000
    const int Etot = E + N;
    const int* srcI = ei;
    const int* dstI = ei + E;

    char* base = (char*)d_ws;
    size_t off = 0;
    auto alloc = [&](size_t bytes) {
        void* p = base + off;
        off = (off + bytes + 255) & ~(size_t)255;
        return p;
    };
    u16* x_bf  = (u16*)alloc((size_t)N * 128 * 2);
    u16* h_bf  = (u16*)alloc((size_t)N * 256 * 2);
    u16* oa_bf = (u16*)alloc((size_t)N * 256 * 2);
    u16* ob_bf = (u16*)alloc((size_t)N * 256 * 2);
    u16* w1t   = (u16*)alloc(256 * 128 * 2);
    u16* w2t   = (u16*)alloc(256 * 256 * 2);
    float* h3   = (float*)alloc((size_t)N * 10 * 4);
    float* o3   = (float*)alloc((size_t)N * 10 * 4);
    float* al_s = (float*)alloc((size_t)N * 4 * 4);
    float* al_d = (float*)alloc((size_t)N * 4 * 4);
    int* cnt    = (int*)alloc((size_t)N * 4);
    int* rp     = (int*)alloc((size_t)(N + 1) * 4);
    int* cursor = (int*)alloc((size_t)N * 4);
    int* srcp   = (int*)alloc((size_t)Etot * 4);
    float* pooled = (float*)alloc(64);

    // ---- preprocessing: casts, transposes, CSR ----
    cast_f2b4<<<(N * 128 / 4 + 255) / 256, 256, 0, stream>>>(x, x_bf, N * 128 / 4);
    transpose_w<<<(128 * 256 + 255) / 256, 256, 0, stream>>>(W1, w1t, 128, 256);
    transpose_w<<<(256 * 256 + 255) / 256, 256, 0, stream>>>(W2, w2t, 256, 256);
    hipMemsetAsync(cnt, 0, (size_t)N * sizeof(int), stream);
    deg_hist<<<(Etot + 255) / 256, 256, 0, stream>>>(dstI, E, Etot, cnt);
    scan_excl4<<<1, 1024, 0, stream>>>(cnt, rp, cursor, N);
    csr_scatter<<<(Etot + 255) / 256, 256, 0, stream>>>(srcI, dstI, E, Etot, cursor, srcp);

    const int FUSED_BLOCKS = (N + 3) / 4;
    const int GX = (N + 127) / 128;

    // ---- layer 1: x_bf[N,128] -> oa_bf[N,256], ELU ----
    {
        dim3 g(GX, 2);
        gemm_mfma<<<g, 256, 0, stream>>>(x_bf, w1t, h_bf, N, 128, 256);
        compute_al_b<<<(N * 4 + 255) / 256, 256, 0, stream>>>(h_bf, as1, ad1, N, al_s, al_d);
        gat_fused_h4<true><<<FUSED_BLOCKS, 256, 0, stream>>>(
            h_bf, al_s, al_d, b1, rp, srcp, N, oa_bf);
    }
    // ---- layer 2: oa_bf -> ob_bf, ELU ----
    {
        dim3 g(GX, 2);
        gemm_mfma<<<g, 256, 0, stream>>>(oa_bf, w2t, h_bf, N, 256, 256);
        compute_al_b<<<(N * 4 + 255) / 256, 256, 0, stream>>>(h_bf, as2, ad2, N, al_s, al_d);
        gat_fused_h4<true><<<FUSED_BLOCKS, 256, 0, stream>>>(
            h_bf, al_s, al_d, b2, rp, srcp, N, ob_bf);
    }
    // ---- layer 3: ob_bf[N,256] -> o3[N,10], heads=1, no ELU ----
    {
        gemm3_wave<<<1024, 256, 0, stream>>>(ob_bf, W3, h3, N);
        compute_al_f<<<(N + 255) / 256, 256, 0, stream>>>(h3, as3, ad3, N, al_s, al_d);
        gat_fused_h1<<<FUSED_BLOCKS, 256, 0, stream>>>(
            h3, al_s, al_d, b3, rp, srcp, N, o3);
    }

    hipMemsetAsync(pooled, 0, 16 * sizeof(float), stream);
    mean_pool<<<1024, 256, 0, stream>>>(o3, N, 10, pooled);
    log_softmax_out<<<1, 64, 0, stream>>>(pooled, N, 10, out);
}